// Round 3
// baseline (238.133 us; speedup 1.0000x reference)
//
#include <hip/hip_runtime.h>
#include <math.h>

#define NTOK 16384
#define DIM 2048
#define NEXP 64
#define TB 32              // tokens per block
#define KG 4               // K-groups (wave-level K-split)
#define CPG 16             // chunks of 32 per K-group (4*16 = 64 chunks total)

// flat output offsets (return order)
#define OFF_W    0
#define OFF_I    32768
#define OFF_P    65536
#define OFF_ENT  1114112
#define OFF_CONF 1114113
#define OFF_UTIL 1114114

typedef short s16x8 __attribute__((ext_vector_type(8)));
typedef float f32x4 __attribute__((ext_vector_type(4)));

__device__ __forceinline__ unsigned short f2bf(float v) {
    unsigned u = __builtin_bit_cast(unsigned, v);
    u = u + 0x7FFFu + ((u >> 16) & 1u);          // RNE
    return (unsigned short)(u >> 16);
}
__device__ __forceinline__ float bf2f(unsigned short b) {
    return __builtin_bit_cast(float, (unsigned)b << 16);
}

// Split W into 3 bf16 planes (hi/mid/lo), fragment-linear (verified r4/r5):
// plane p, chunk c, ntile nt, lane l -> uint4 at wsp[p*16384 + c*256 + nt*64 + l]
// fragment element j: W[16nt + (l&15)][32c + 8*(l>>4) + j]
// Grid widened to 256 blocks x 64 threads (same jobs, more CUs busy).
// Also zeroes the 66 stat accumulators.
__global__ void router_wsplit(const float* __restrict__ Wg, uint4* __restrict__ wsp,
                              float* __restrict__ out) {
    const int bid = blockIdx.x;
    const int tid = threadIdx.x;
    const int c   = bid >> 2;
    const int gt  = (bid & 3) * 64 + tid;   // 0..255 within chunk
    if (c == 0 && gt < 66) out[OFF_ENT + gt] = 0.0f;
    const int nt = gt >> 6, l = gt & 63;
    const int e  = 16 * nt + (l & 15);
    const int k0 = 32 * c + 8 * (l >> 4);
    const float* src = Wg + (size_t)e * DIM + k0;
    float4 a = *(const float4*)src;
    float4 b = *(const float4*)(src + 4);
    float v[8] = {a.x, a.y, a.z, a.w, b.x, b.y, b.z, b.w};
    unsigned short H[8], M[8], L[8];
    #pragma unroll
    for (int j = 0; j < 8; ++j) {
        H[j] = f2bf(v[j]);  float r = v[j] - bf2f(H[j]);
        M[j] = f2bf(r);     r = r - bf2f(M[j]);
        L[j] = f2bf(r);
    }
    uint4 ph, pm, pl;
    ph.x = H[0] | ((unsigned)H[1] << 16); ph.y = H[2] | ((unsigned)H[3] << 16);
    ph.z = H[4] | ((unsigned)H[5] << 16); ph.w = H[6] | ((unsigned)H[7] << 16);
    pm.x = M[0] | ((unsigned)M[1] << 16); pm.y = M[2] | ((unsigned)M[3] << 16);
    pm.z = M[4] | ((unsigned)M[5] << 16); pm.w = M[6] | ((unsigned)M[7] << 16);
    pl.x = L[0] | ((unsigned)L[1] << 16); pl.y = L[2] | ((unsigned)L[3] << 16);
    pl.z = L[4] | ((unsigned)L[5] << 16); pl.w = L[6] | ((unsigned)L[7] << 16);
    const int idx = c * 256 + gt;
    wsp[idx]         = ph;
    wsp[16384 + idx] = pm;
    wsp[32768 + idx] = pl;
}

// W fragments for this wave's 2 ntiles x 3 planes, chunk (g*CPG + i_).
// wb = wq + (g*CPG)*256 + np*128 + l  (uint4 units)
#define LOADW6(W_, i_) {                         \
    W_[0] = wb[(i_) * 256];                      \
    W_[1] = wb[(i_) * 256 + 64];                 \
    W_[2] = wb[(i_) * 256 + 16384];              \
    W_[3] = wb[(i_) * 256 + 16384 + 64];         \
    W_[4] = wb[(i_) * 256 + 32768];              \
    W_[5] = wb[(i_) * 256 + 32768 + 64]; }

// x A-fragments for both token-tiles, chunk i_ of this wave's K-group.
#define LOADX4(X_, i_) {                                   \
    X_[0] = *(const float4*)(xb0 + (i_) * 32);             \
    X_[1] = *(const float4*)(xb0 + (i_) * 32 + 4);         \
    X_[2] = *(const float4*)(xb1 + (i_) * 32);             \
    X_[3] = *(const float4*)(xb1 + (i_) * 32 + 4); }

// exact truncation split of 8 fp32 -> 3 bf16 frags (identical math to verified kernels)
#define CONVA(a0_, a1_) {                                                \
    float xv[8];                                                         \
    xv[0]=a0_.x; xv[1]=a0_.y; xv[2]=a0_.z; xv[3]=a0_.w;                  \
    xv[4]=a1_.x; xv[5]=a1_.y; xv[6]=a1_.z; xv[7]=a1_.w;                  \
    _Pragma("unroll")                                                    \
    for (int j = 0; j < 8; ++j) {                                        \
        unsigned u_  = __builtin_bit_cast(unsigned, xv[j]);              \
        unsigned hb_ = u_ & 0xFFFF0000u;                                 \
        float    r_  = xv[j] - __builtin_bit_cast(float, hb_);           \
        unsigned mb_ = __builtin_bit_cast(unsigned, r_) & 0xFFFF0000u;   \
        float    r2_ = r_ - __builtin_bit_cast(float, mb_);              \
        unsigned lb_ = __builtin_bit_cast(unsigned, r2_);                \
        ah[j] = (short)(hb_ >> 16);                                      \
        am[j] = (short)(mb_ >> 16);                                      \
        al[j] = (short)(lb_ >> 16);                                      \
    } }

// 12 MFMAs: one token-tile x 2 ntiles x 6 products {hh,mh,hm,mm,hl,lh}.
// Per-acc product order identical to verified kernels.
#define COMPUTE12(W_, aE_, aO_) {                                        \
    s16x8 b0h_ = __builtin_bit_cast(s16x8, W_[0]);                       \
    s16x8 b1h_ = __builtin_bit_cast(s16x8, W_[1]);                       \
    s16x8 b0m_ = __builtin_bit_cast(s16x8, W_[2]);                       \
    s16x8 b1m_ = __builtin_bit_cast(s16x8, W_[3]);                       \
    s16x8 b0l_ = __builtin_bit_cast(s16x8, W_[4]);                       \
    s16x8 b1l_ = __builtin_bit_cast(s16x8, W_[5]);                       \
    aE_ = __builtin_amdgcn_mfma_f32_16x16x32_bf16(ah, b0h_, aE_, 0, 0, 0); \
    aO_ = __builtin_amdgcn_mfma_f32_16x16x32_bf16(ah, b1h_, aO_, 0, 0, 0); \
    aE_ = __builtin_amdgcn_mfma_f32_16x16x32_bf16(am, b0h_, aE_, 0, 0, 0); \
    aO_ = __builtin_amdgcn_mfma_f32_16x16x32_bf16(am, b1h_, aO_, 0, 0, 0); \
    aE_ = __builtin_amdgcn_mfma_f32_16x16x32_bf16(ah, b0m_, aE_, 0, 0, 0); \
    aO_ = __builtin_amdgcn_mfma_f32_16x16x32_bf16(ah, b1m_, aO_, 0, 0, 0); \
    aE_ = __builtin_amdgcn_mfma_f32_16x16x32_bf16(am, b0m_, aE_, 0, 0, 0); \
    aO_ = __builtin_amdgcn_mfma_f32_16x16x32_bf16(am, b1m_, aO_, 0, 0, 0); \
    aE_ = __builtin_amdgcn_mfma_f32_16x16x32_bf16(ah, b0l_, aE_, 0, 0, 0); \
    aO_ = __builtin_amdgcn_mfma_f32_16x16x32_bf16(ah, b1l_, aO_, 0, 0, 0); \
    aE_ = __builtin_amdgcn_mfma_f32_16x16x32_bf16(al, b0h_, aE_, 0, 0, 0); \
    aO_ = __builtin_amdgcn_mfma_f32_16x16x32_bf16(al, b1h_, aO_, 0, 0, 0); \
    }

// 512 threads = 8 waves = 4 K-groups x 2 expert-pairs; each wave does BOTH
// token-tiles. Barrier-free K-loop: x direct from global (L3), W from L2,
// split in-register. Epilogue combines 4 K-partials in LDS.
__global__ __launch_bounds__(512, 4) void router_main(
    const float* __restrict__ x, const uint4* __restrict__ wq,
    float* __restrict__ out)
{
    __shared__ float lg[TB][NEXP + 1];
    __shared__ float m1s[TB], rss[TB];
    __shared__ float s_ent, s_conf, s_cnt[NEXP];

    const int tid = threadIdx.x;
    const int l   = tid & 63;
    const int w   = tid >> 6;                                // 0..7
    const int g   = __builtin_amdgcn_readfirstlane(w >> 1);  // K-group 0..3
    const int np  = __builtin_amdgcn_readfirstlane(w & 1);   // expert-pair
    const int qd  = l >> 4;                                  // K-octet 0..3
    const int tr  = l & 15;                                  // token row in tile
    const int t0  = blockIdx.x * TB;

    if (tid == 0) { s_ent = 0.0f; s_conf = 0.0f; }
    if (tid < NEXP) s_cnt[tid] = 0.0f;

    // per-lane bases
    const float* xb0 = x + (size_t)(t0 + tr) * DIM + g * (CPG * 32) + 8 * qd;
    const float* xb1 = xb0 + 16 * DIM;
    const uint4* wb  = wq + (size_t)(g * CPG) * 256 + np * 128 + l;

    f32x4 a00 = (f32x4)(0.0f), a01 = (f32x4)(0.0f);
    f32x4 a10 = (f32x4)(0.0f), a11 = (f32x4)(0.0f);
    s16x8 ah, am, al;
    uint4 wA[6], wB[6];
    float4 xA[4], xB[4];

    // prologue: 2 chunks in flight
    LOADW6(wA, 0); LOADX4(xA, 0);
    LOADW6(wB, 1); LOADX4(xB, 1);

    #pragma unroll
    for (int i = 0; i < CPG; i += 2) {
        // chunk i
        CONVA(xA[0], xA[1]);  COMPUTE12(wA, a00, a01);
        CONVA(xA[2], xA[3]);  COMPUTE12(wA, a10, a11);
        if (i + 2 < CPG) { LOADW6(wA, i + 2); LOADX4(xA, i + 2); }
        // chunk i+1
        CONVA(xB[0], xB[1]);  COMPUTE12(wB, a00, a01);
        CONVA(xB[2], xB[3]);  COMPUTE12(wB, a10, a11);
        if (i + 3 < CPG) { LOADW6(wB, i + 3); LOADX4(xB, i + 3); }
    }

    // combine 4 K-group partials in lg.
    // C/D layout (verified): col = lane&15 (expert), row = 4*qd + r (token)
#define WRROWS(op_) { _Pragma("unroll")                                  \
    for (int r = 0; r < 4; ++r) {                                        \
        lg[4 * qd + r][np * 32 + tr]           op_ a00[r];               \
        lg[4 * qd + r][np * 32 + 16 + tr]      op_ a01[r];               \
        lg[16 + 4 * qd + r][np * 32 + tr]      op_ a10[r];               \
        lg[16 + 4 * qd + r][np * 32 + 16 + tr] op_ a11[r];               \
    } }
    if (g == 3) WRROWS(=);
    __syncthreads();
    if (g == 2) WRROWS(+=);
    __syncthreads();
    if (g == 1) WRROWS(+=);
    __syncthreads();
    if (g == 0) WRROWS(+=);
    __syncthreads();
#undef WRROWS

    // 32 threads: top-2 + softmax stats per token
    if (tid < TB) {
        const int t = tid;
        float m1 = -INFINITY, m2 = -INFINITY;
        int i1 = 0, i2 = 0;
        for (int e = 0; e < NEXP; ++e) {
            float lv = lg[t][e];
            if (lv > m1)      { m2 = m1; i2 = i1; m1 = lv; i1 = e; }
            else if (lv > m2) { m2 = lv; i2 = e; }
        }
        float ssum = 0.0f, tsum = 0.0f;
        for (int e = 0; e < NEXP; ++e) {
            float d = lg[t][e] - m1;
            float ex = __expf(d);
            ssum += ex;
            tsum += d * ex;
        }
        float rs = 1.0f / ssum;
        float H  = logf(ssum) - tsum * rs;   // H = ln(s) - (sum d e^d)/s
        float e2 = __expf(m2 - m1);
        float rn = 1.0f / (1.0f + e2);
        float w0 = rn, w1v = e2 * rn;
        m1s[t] = m1; rss[t] = rs;

        *(float2*)&out[OFF_W + 2 * (t0 + t)] = make_float2(w0, w1v);
        *(float2*)&out[OFF_I + 2 * (t0 + t)] = make_float2((float)i1, (float)i2);

        atomicAdd(&s_ent,  H);
        atomicAdd(&s_conf, w0);
        atomicAdd(&s_cnt[i1], 1.0f);
        atomicAdd(&s_cnt[i2], 1.0f);
    }
    __syncthreads();

    // coalesced probs write: 512 float4s / 512 threads
    {
        int t  = tid >> 4;
        int qq = tid & 15;
        float m  = m1s[t];
        float rs = rss[t];
        float4 pr;
        pr.x = __expf(lg[t][4 * qq + 0] - m) * rs;
        pr.y = __expf(lg[t][4 * qq + 1] - m) * rs;
        pr.z = __expf(lg[t][4 * qq + 2] - m) * rs;
        pr.w = __expf(lg[t][4 * qq + 3] - m) * rs;
        *(float4*)&out[OFF_P + (size_t)(t0 + t) * NEXP + 4 * qq] = pr;
    }

    // stats: pre-scaled so the atomic sums are exact / final means
    if (tid == 0) {
        atomicAdd(&out[OFF_ENT],  s_ent  * (1.0f / 16384.0f));
        atomicAdd(&out[OFF_CONF], s_conf * (1.0f / 16384.0f));
    }
    if (tid < NEXP)
        atomicAdd(&out[OFF_UTIL + tid], s_cnt[tid] * (1.0f / 32768.0f));
}

extern "C" void kernel_launch(void* const* d_in, const int* in_sizes, int n_in,
                              void* d_out, int out_size, void* d_ws, size_t ws_size,
                              hipStream_t stream) {
    const float* x  = (const float*)d_in[0];
    const float* Wg = (const float*)d_in[1];
    float* out = (float*)d_out;
    (void)in_sizes; (void)n_in; (void)out_size; (void)ws_size;

    router_wsplit<<<dim3(256), dim3(64), 0, stream>>>(Wg, (uint4*)d_ws, out);
    router_main<<<dim3(NTOK / TB), dim3(512), 0, stream>>>(x, (const uint4*)d_ws, out);
}